// Round 3
// baseline (396.702 us; speedup 1.0000x reference)
//
#include <hip/hip_runtime.h>

#define BB 64
#define NN 8192
#define MM 128
#define HH 512
#define KLSTM 896   // 384 (x|pr0|pr1) + 512 (h0)
#define JTOT 2048
#define COLS 658    // 134 (ro0) + 390 (wo0) + 134 (ro1)
#define OUTN 128
#define CHUNKS 32   // 8192/32 = 256 rows per chunk

__device__ __forceinline__ float sigf(float x){ return 1.0f/(1.0f+__expf(-x)); }
__device__ __forceinline__ float tanhf_f(float x){ return 1.0f - 2.0f/(__expf(2.0f*x)+1.0f); }
__device__ __forceinline__ float softplusf_(float x){ return (x>20.0f)? x : log1pf(expf(x)); }

// ---------- 1. LSTM gemm (inp built on the fly): gates[b][j] ----------
__global__ __launch_bounds__(1024) void k_lstm_gemm(
    const float* __restrict__ x, const float* __restrict__ pr,
    const float* __restrict__ h0,
    const float* __restrict__ Wih, const float* __restrict__ Whh,
    const float* __restrict__ bih, const float* __restrict__ bhh,
    float* __restrict__ gates)
{
  __shared__ float inp_s[64*65];   // [k][b]
  __shared__ float w_s[64*68];     // [k][j]
  int tid = threadIdx.x;
  int b = tid & 63, jl = tid >> 6;      // jl 0..15, owns 4 consecutive j
  int jbase = blockIdx.x*64;
  float ax=0.f, ay=0.f, az=0.f, aw=0.f;
  for (int kc=0; kc<KLSTM; kc+=64){
    #pragma unroll
    for (int i=0;i<4;i++){
      int idx = tid + i*1024;
      int kk = idx & 63, p = idx >> 6;
      int kglob = kc + kk;
      float iv;
      if (kglob < 128)      iv = x[p*128 + kglob];
      else if (kglob < 256) iv = pr[p*MM + (kglob-128)];
      else if (kglob < 384) iv = pr[BB*MM + p*MM + (kglob-256)];
      else                  iv = h0[p*HH + (kglob-384)];
      inp_s[kk*65+p] = iv;
      float wv = (kglob < 384) ? Wih[(size_t)(jbase+p)*384 + kglob]
                               : Whh[(size_t)(jbase+p)*512 + (kglob-384)];
      w_s[kk*68 + p] = wv;
    }
    __syncthreads();
    #pragma unroll 8
    for (int kk=0; kk<64; ++kk){
      float a = inp_s[kk*65 + b];
      const float4 w4 = *(const float4*)&w_s[kk*68 + jl*4];
      ax += a*w4.x; ay += a*w4.y; az += a*w4.z; aw += a*w4.w;
    }
    __syncthreads();
  }
  int j0 = jbase + jl*4;
  float4 o;
  o.x = ax + bih[j0+0] + bhh[j0+0];
  o.y = ay + bih[j0+1] + bhh[j0+1];
  o.z = az + bih[j0+2] + bhh[j0+2];
  o.w = aw + bih[j0+3] + bhh[j0+3];
  *(float4*)&gates[(size_t)b*JTOT + j0] = o;
}

// ---------- 2. head gemm (LSTM activation fused into staging) ----------
__global__ __launch_bounds__(1024) void k_head_gemm(
    const float* __restrict__ gates, const float* __restrict__ c0,
    const float* __restrict__ Wr, const float* __restrict__ br,
    const float* __restrict__ Ww, const float* __restrict__ bw,
    float* __restrict__ roall)
{
  __shared__ float c_s[64*65];   // [k][b]
  __shared__ float w_s[64*68];   // [k][col]
  int tid = threadIdx.x;
  int b = tid & 63, cl = tid >> 6;
  int cbase = blockIdx.x*64;
  float ac[4] = {0.f,0.f,0.f,0.f};
  for (int kc=0; kc<HH; kc+=64){
    #pragma unroll
    for (int i=0;i<4;i++){
      int idx = tid + i*1024;
      int kk = idx & 63, p = idx >> 6;
      int h = kc + kk;
      const float* g = gates + (size_t)p*JTOT;
      float i_ = sigf(g[h]);
      float f_ = sigf(g[HH + h]);
      float gg = tanhf_f(g[2*HH + h]);
      float o_ = sigf(g[3*HH + h]);
      float cn = f_*c0[p*HH + h] + i_*gg;
      c_s[kk*65+p] = o_*tanhf_f(cn);
      int col = cbase + p;
      float wv = 0.0f;
      if (col < 134)       wv = Wr[(size_t)col*HH + h];
      else if (col < 524)  wv = Ww[(size_t)(col-134)*HH + h];
      else if (col < COLS) wv = Wr[(size_t)(134 + col-524)*HH + h];
      w_s[kk*68 + p] = wv;
    }
    __syncthreads();
    #pragma unroll 8
    for (int kk=0; kk<64; ++kk){
      float a = c_s[kk*65 + b];
      const float4 w4 = *(const float4*)&w_s[kk*68 + cl*4];
      ac[0] += a*w4.x; ac[1] += a*w4.y; ac[2] += a*w4.z; ac[3] += a*w4.w;
    }
    __syncthreads();
  }
  #pragma unroll
  for (int t=0;t<4;t++){
    int col = cbase + cl*4 + t;
    if (col < COLS){
      float bias = (col<134)? br[col] : (col<524)? bw[col-134] : br[134 + col-524];
      roall[(size_t)b*COLS + col] = ac[t] + bias;
    }
  }
}

// ---------- 3. param extraction ----------
// roall: [ro0: 0..133 | wo0: 134..523 | ro1: 524..657]
// scal: [4][BB][8]; rows 0=r0,1=w0,2=r1: {beta,g,s0,s1,s2,gamma,knorm,-};
//       row 3: {a.kr1, a.a, -,...}
__global__ void k_params(const float* __restrict__ roall,
                         float* __restrict__ kr0, float* __restrict__ kw0,
                         float* __restrict__ kr1, float* __restrict__ E,
                         float* __restrict__ E2, float* __restrict__ A,
                         float* __restrict__ AE, float* __restrict__ EKR1,
                         float* __restrict__ scal)
{
  int b = blockIdx.x;
  int m = threadIdx.x;   // 128
  const float* ro = roall + (size_t)b*COLS;
  float k0 = ro[m], kw = ro[134+m], k1 = ro[524+m];
  float e  = sigf(ro[268+m]);
  float a  = ro[396+m];
  kr0[b*MM+m]=k0; kw0[b*MM+m]=kw; kr1[b*MM+m]=k1;
  E[b*MM+m]=e; E2[b*MM+m]=e*e; A[b*MM+m]=a; AE[b*MM+m]=a*e; EKR1[b*MM+m]=e*k1;
  if (m < 3){
    int base = (m==0)? 0 : (m==1)? 134 : 524;
    float beta  = softplusf_(ro[base+128]);
    float g     = sigf(ro[base+129]);
    float s0r = ro[base+130], s1r = ro[base+131], s2r = ro[base+132];
    float mx = fmaxf(s0r, fmaxf(s1r, s2r));
    float es0 = __expf(s0r-mx), es1 = __expf(s1r-mx), es2 = __expf(s2r-mx);
    float es = es0+es1+es2;
    float gamma = 1.0f + softplusf_(ro[base+133]);
    float ss = 0.f;
    for (int t=0;t<MM;t++){ float kv = ro[base+t]; ss += kv*kv; }
    float kn = fmaxf(sqrtf(ss), 1e-8f);
    float* sc = scal + ((size_t)m*BB + b)*8;
    sc[0]=beta; sc[1]=g; sc[2]=es0/es; sc[3]=es1/es; sc[4]=es2/es; sc[5]=gamma; sc[6]=kn;
  }
  if (m == 3){
    float s = 0.f;
    for (int t=0;t<MM;t++) s += ro[396+t]*ro[524+t];
    scal[((size_t)3*BB + b)*8 + 0] = s;     // a . kr1
  }
  if (m == 4){
    float s = 0.f;
    for (int t=0;t<MM;t++) s += ro[396+t]*ro[396+t];
    scal[((size_t)3*BB + b)*8 + 1] = s;     // a . a
  }
}

// ---------- 4. pass A: single read of mem0, 9 per-row scalars ----------
// OUT9 layout [q][b][n], q: 0=v.kr0 1=v.kw0 2=|v|^2 3=v.kr1 4=v.(e*kr1)
//                         5=sum v^2 e  6=sum v^2 e^2  7=v.a  8=v.(a*e)
__global__ __launch_bounds__(256) void k_passA(
    const float* __restrict__ mem, const float* __restrict__ kr0,
    const float* __restrict__ kw0, const float* __restrict__ kr1,
    const float* __restrict__ EKR1, const float* __restrict__ E,
    const float* __restrict__ E2, const float* __restrict__ A,
    const float* __restrict__ AE, float* __restrict__ OUT9)
{
  const size_t S = (size_t)BB*NN;
  int b = blockIdx.y, chunk = blockIdx.x;
  int tid = threadIdx.x, ty = tid>>5, lane = tid&31;
  float4 c0 = ((const float4*)(kr0  + (size_t)b*MM))[lane];
  float4 c1 = ((const float4*)(kw0  + (size_t)b*MM))[lane];
  float4 c3 = ((const float4*)(kr1  + (size_t)b*MM))[lane];
  float4 c4 = ((const float4*)(EKR1 + (size_t)b*MM))[lane];
  float4 c5 = ((const float4*)(E    + (size_t)b*MM))[lane];
  float4 c6 = ((const float4*)(E2   + (size_t)b*MM))[lane];
  float4 c7 = ((const float4*)(A    + (size_t)b*MM))[lane];
  float4 c8 = ((const float4*)(AE   + (size_t)b*MM))[lane];
  for (int it=0; it<32; ++it){
    int n = chunk*256 + it*8 + ty;
    size_t p = (size_t)b*NN + n;
    const float4* row = (const float4*)(mem + p*MM);
    float4 v = row[lane];
    float4 vv; vv.x=v.x*v.x; vv.y=v.y*v.y; vv.z=v.z*v.z; vv.w=v.w*v.w;
    float r[9];
    r[0] = v.x*c0.x + v.y*c0.y + v.z*c0.z + v.w*c0.w;
    r[1] = v.x*c1.x + v.y*c1.y + v.z*c1.z + v.w*c1.w;
    r[2] = vv.x + vv.y + vv.z + vv.w;
    r[3] = v.x*c3.x + v.y*c3.y + v.z*c3.z + v.w*c3.w;
    r[4] = v.x*c4.x + v.y*c4.y + v.z*c4.z + v.w*c4.w;
    r[5] = vv.x*c5.x + vv.y*c5.y + vv.z*c5.z + vv.w*c5.w;
    r[6] = vv.x*c6.x + vv.y*c6.y + vv.z*c6.z + vv.w*c6.w;
    r[7] = v.x*c7.x + v.y*c7.y + v.z*c7.z + v.w*c7.w;
    r[8] = v.x*c8.x + v.y*c8.y + v.z*c8.z + v.w*c8.w;
    #pragma unroll
    for (int q=0;q<9;q++){
      #pragma unroll
      for (int off=16; off; off>>=1) r[q] += __shfl_xor(r[q], off);
    }
    if (lane==0){
      #pragma unroll
      for (int q=0;q<9;q++) OUT9[(size_t)q*S + p] = r[q];
    }
  }
}

// ---------- 5. addressing head 0 (read & write roles) ----------
__global__ __launch_bounds__(256) void k_addr0(
    const float* __restrict__ OUT9, const float* __restrict__ scal,
    const float* __restrict__ pwr, const float* __restrict__ pww,
    float* __restrict__ wout)
{
  const size_t S = (size_t)BB*NN;
  int b = blockIdx.x, which = blockIdx.y;
  const float* numb = OUT9 + (size_t)which*S + (size_t)b*NN;
  const float* ssb  = OUT9 + 2*S + (size_t)b*NN;
  const float* wprev = ((which==0)? pwr : pww) + (size_t)b*NN;
  float* wo = wout + (size_t)which*S + (size_t)b*NN;
  const float* sc = scal + ((size_t)which*BB + b)*8;
  float beta=sc[0], g=sc[1], s0=sc[2], s1=sc[3], s2=sc[4], gamma=sc[5], kn=sc[6];

  __shared__ float buf[NN];
  __shared__ float red[256];
  int tid = threadIdx.x;

  float lmax = -1e30f;
  for (int n=tid; n<NN; n+=256){
    float den = fmaxf(sqrtf(ssb[n]), 1e-8f) * kn;
    float l = beta * numb[n] / den;
    buf[n] = l;
    lmax = fmaxf(lmax, l);
  }
  red[tid] = lmax; __syncthreads();
  for (int s=128; s>0; s>>=1){ if (tid<s) red[tid]=fmaxf(red[tid],red[tid+s]); __syncthreads(); }
  lmax = red[0]; __syncthreads();
  float lsum = 0.f;
  for (int n=tid; n<NN; n+=256){ float e = __expf(buf[n]-lmax); buf[n]=e; lsum+=e; }
  red[tid] = lsum; __syncthreads();
  for (int s=128; s>0; s>>=1){ if (tid<s) red[tid]+=red[tid+s]; __syncthreads(); }
  float inv = 1.0f/red[0]; __syncthreads();
  for (int n=tid; n<NN; n+=256){ float wc = buf[n]*inv; buf[n] = g*wc + (1.0f-g)*wprev[n]; }
  __syncthreads();
  float wt_loc[32];
  float psum = 0.f;
  #pragma unroll
  for (int i=0;i<32;i++){
    int n = tid + i*256;
    float wm = buf[(n-1)&(NN-1)];
    float w0 = buf[n];
    float wp = buf[(n+1)&(NN-1)];
    float wt = s0*wm + s1*w0 + s2*wp;
    float p = __expf(gamma*__logf(wt));
    wt_loc[i] = p; psum += p;
  }
  red[tid] = psum; __syncthreads();
  for (int s=128; s>0; s>>=1){ if (tid<s) red[tid]+=red[tid+s]; __syncthreads(); }
  float invp = 1.0f/(red[0] + 1e-16f);
  #pragma unroll
  for (int i=0;i<32;i++) wo[tid + i*256] = wt_loc[i]*invp;
}

// ---------- 6. addressing head 1 read (num/norm reconstructed, no mem read) ----------
__global__ __launch_bounds__(256) void k_addr1(
    const float* __restrict__ OUT9, const float* __restrict__ ww0,
    const float* __restrict__ scal, const float* __restrict__ wprev,
    float* __restrict__ wout)
{
  const size_t S = (size_t)BB*NN;
  int b = blockIdx.x;
  const float* pb  = OUT9 + (size_t)b*NN;
  const float* wwb = ww0 + (size_t)b*NN;
  const float* wp  = wprev + (size_t)b*NN;
  float* wo = wout + (size_t)b*NN;
  const float* sc = scal + ((size_t)2*BB + b)*8;
  float beta=sc[0], g=sc[1], s0=sc[2], s1=sc[3], s2=sc[4], gamma=sc[5], kn=sc[6];
  const float* sc3 = scal + ((size_t)3*BB + b)*8;
  float akr1 = sc3[0], aa = sc3[1];

  __shared__ float buf[NN];
  __shared__ float red[256];
  int tid = threadIdx.x;

  float lmax = -1e30f;
  for (int n=tid; n<NN; n+=256){
    float ss = pb[2*S+n], t3 = pb[3*S+n], t4 = pb[4*S+n];
    float t5 = pb[5*S+n], t6 = pb[6*S+n], t7 = pb[7*S+n], t8 = pb[8*S+n];
    float w = wwb[n];
    float num  = t3 + w*(akr1 - t4);
    float n1sq = ss + 2.0f*w*(t7 - t5) + w*w*(t6 + aa - 2.0f*t8);
    float nrm = sqrtf(fmaxf(n1sq, 0.f));
    float l = beta * num / (fmaxf(nrm, 1e-8f) * kn);
    buf[n] = l;
    lmax = fmaxf(lmax, l);
  }
  red[tid] = lmax; __syncthreads();
  for (int s=128; s>0; s>>=1){ if (tid<s) red[tid]=fmaxf(red[tid],red[tid+s]); __syncthreads(); }
  lmax = red[0]; __syncthreads();
  float lsum = 0.f;
  for (int n=tid; n<NN; n+=256){ float e = __expf(buf[n]-lmax); buf[n]=e; lsum+=e; }
  red[tid] = lsum; __syncthreads();
  for (int s=128; s>0; s>>=1){ if (tid<s) red[tid]+=red[tid+s]; __syncthreads(); }
  float inv = 1.0f/red[0]; __syncthreads();
  for (int n=tid; n<NN; n+=256){ float wc = buf[n]*inv; buf[n] = g*wc + (1.0f-g)*wp[n]; }
  __syncthreads();
  float wt_loc[32];
  float psum = 0.f;
  #pragma unroll
  for (int i=0;i<32;i++){
    int n = tid + i*256;
    float wm = buf[(n-1)&(NN-1)];
    float w0 = buf[n];
    float wpv = buf[(n+1)&(NN-1)];
    float wt = s0*wm + s1*w0 + s2*wpv;
    float p = __expf(gamma*__logf(wt));
    wt_loc[i] = p; psum += p;
  }
  red[tid] = psum; __syncthreads();
  for (int s=128; s>0; s>>=1){ if (tid<s) red[tid]+=red[tid+s]; __syncthreads(); }
  float invp = 1.0f/(red[0] + 1e-16f);
  #pragma unroll
  for (int i=0;i<32;i++) wo[tid + i*256] = wt_loc[i]*invp;
}

// ---------- 7. pass F: second read of mem0, 3 weighted row-sums + w2 ----------
// PART layout [b][chunk][3][128]; W2P [b][chunk]
__global__ __launch_bounds__(256) void k_passF(
    const float* __restrict__ mem, const float* __restrict__ wr0,
    const float* __restrict__ wr1, const float* __restrict__ ww0,
    float* __restrict__ part, float* __restrict__ w2p)
{
  int b = blockIdx.y, chunk = blockIdx.x;
  int tid = threadIdx.x, ty = tid>>5, lane = tid&31;
  float4 a0 = {0.f,0.f,0.f,0.f}, a1 = a0, a2 = a0;
  float w2 = 0.f;
  for (int it=0; it<32; ++it){
    int n = chunk*256 + it*8 + ty;
    size_t p = (size_t)b*NN + n;
    const float4* row = (const float4*)(mem + p*MM);
    float4 v = row[lane];
    float w0r = wr0[p], w1r = wr1[p], wwr = ww0[p];
    float w12 = w1r*wwr;
    a0.x += w0r*v.x; a0.y += w0r*v.y; a0.z += w0r*v.z; a0.w += w0r*v.w;
    a1.x += w1r*v.x; a1.y += w1r*v.y; a1.z += w1r*v.z; a1.w += w1r*v.w;
    a2.x += w12*v.x; a2.y += w12*v.y; a2.z += w12*v.z; a2.w += w12*v.w;
    if (lane==0) w2 += w12;
  }
  __shared__ float4 sred[256];
  __shared__ float w2s[8];
  float4 accs[3] = {a0,a1,a2};
  #pragma unroll
  for (int q=0;q<3;q++){
    sred[tid] = accs[q];
    __syncthreads();
    if (ty == 0){
      float4 s = {0.f,0.f,0.f,0.f};
      #pragma unroll
      for (int r=0;r<8;r++){
        float4 t = sred[r*32 + lane];
        s.x += t.x; s.y += t.y; s.z += t.z; s.w += t.w;
      }
      ((float4*)(part + (((size_t)(b*CHUNKS + chunk))*3 + q)*MM))[lane] = s;
    }
    __syncthreads();
  }
  if (lane==0) w2s[ty] = w2;
  __syncthreads();
  if (tid==0){
    float s = 0.f;
    #pragma unroll
    for (int r=0;r<8;r++) s += w2s[r];
    w2p[b*CHUNKS + chunk] = s;
  }
}

// ---------- 8. reduce partials -> inp2T[k][b] (read0 | read1) ----------
__global__ void k_reduce(const float* __restrict__ part, const float* __restrict__ w2p,
                         const float* __restrict__ E, const float* __restrict__ A,
                         float* __restrict__ inp2T)
{
  int b = blockIdx.x; int m = threadIdx.x;   // 128
  float s0=0.f, s1=0.f, s2=0.f;
  for (int c=0;c<CHUNKS;c++){
    const float* pp = part + ((size_t)(b*CHUNKS + c))*3*MM;
    s0 += pp[0*MM + m];
    s1 += pp[1*MM + m];
    s2 += pp[2*MM + m];
  }
  __shared__ float w2sh;
  if (m==0){
    float w=0.f;
    for (int c=0;c<CHUNKS;c++) w += w2p[b*CHUNKS + c];
    w2sh = w;
  }
  __syncthreads();
  float e = E[b*MM+m], a = A[b*MM+m];
  float read0 = s0;
  float read1 = s1 - e*s2 + w2sh*a;
  inp2T[(size_t)m*BB + b] = read0;
  inp2T[(size_t)(MM+m)*BB + b] = read1;
}

// ---------- 9. fc + sigmoid ----------
__global__ void k_fc(const float* __restrict__ inp2T, const float* __restrict__ fcW,
                     const float* __restrict__ fcb, float* __restrict__ out)
{
  int tid = threadIdx.x;
  int b = tid & 63, ol = tid >> 6;       // 4 o per block
  int o = blockIdx.x*4 + ol;
  float acc = fcb[o];
  #pragma unroll 4
  for (int k=0;k<2*MM;k++){
    acc += fcW[(size_t)o*(2*MM) + k] * inp2T[(size_t)k*BB + b];
  }
  out[(size_t)b*OUTN + o] = sigf(acc);
}

extern "C" void kernel_launch(void* const* d_in, const int* in_sizes, int n_in,
                              void* d_out, int out_size, void* d_ws, size_t ws_size,
                              hipStream_t stream) {
  const float* x   = (const float*)d_in[0];
  const float* pr  = (const float*)d_in[1];
  const float* h0  = (const float*)d_in[2];
  const float* c0  = (const float*)d_in[3];
  const float* pwr = (const float*)d_in[4];
  const float* pww = (const float*)d_in[5];
  const float* mem = (const float*)d_in[6];
  const float* Wih = (const float*)d_in[7];
  const float* Whh = (const float*)d_in[8];
  const float* bih = (const float*)d_in[9];
  const float* bhh = (const float*)d_in[10];
  const float* Wr  = (const float*)d_in[11];
  const float* br  = (const float*)d_in[12];
  const float* Ww  = (const float*)d_in[13];
  const float* bw  = (const float*)d_in[14];
  const float* fcW = (const float*)d_in[15];
  const float* fcb = (const float*)d_in[16];
  float* out = (float*)d_out;

  float* ws = (float*)d_ws;
  size_t off = 0;
  auto alloc = [&](size_t n){ float* p = ws + off; off += n; return p; };
  const size_t S = (size_t)BB*NN;
  float* GATES = alloc((size_t)BB*JTOT);
  float* ROALL = alloc((size_t)BB*COLS);
  float* KR0   = alloc((size_t)BB*MM);
  float* KW0   = alloc((size_t)BB*MM);
  float* KR1   = alloc((size_t)BB*MM);
  float* E     = alloc((size_t)BB*MM);
  float* E2    = alloc((size_t)BB*MM);
  float* A     = alloc((size_t)BB*MM);
  float* AE    = alloc((size_t)BB*MM);
  float* EKR1  = alloc((size_t)BB*MM);
  float* SCAL  = alloc((size_t)4*BB*8);
  float* OUT9  = alloc(9*S);
  float* WR0   = alloc(S);
  float* WW0   = alloc(S);     // must stay adjacent to WR0
  float* WR1   = alloc(S);
  float* PART  = alloc((size_t)BB*CHUNKS*3*MM);
  float* W2P   = alloc((size_t)BB*CHUNKS);
  float* INP2T = alloc((size_t)2*MM*BB);
  (void)ws_size; (void)in_sizes; (void)n_in; (void)out_size; (void)WW0;

  k_lstm_gemm<<<JTOT/64, 1024, 0, stream>>>(x, pr, h0, Wih, Whh, bih, bhh, GATES);
  k_head_gemm<<<(COLS+63)/64, 1024, 0, stream>>>(GATES, c0, Wr, br, Ww, bw, ROALL);
  k_params<<<BB, 128, 0, stream>>>(ROALL, KR0, KW0, KR1, E, E2, A, AE, EKR1, SCAL);
  k_passA<<<dim3(CHUNKS,BB), 256, 0, stream>>>(mem, KR0, KW0, KR1, EKR1, E, E2, A, AE, OUT9);
  k_addr0<<<dim3(BB,2), 256, 0, stream>>>(OUT9, SCAL, pwr, pww, WR0);
  k_addr1<<<BB, 256, 0, stream>>>(OUT9, WW0, SCAL, pwr + S, WR1);
  k_passF<<<dim3(CHUNKS,BB), 256, 0, stream>>>(mem, WR0, WR1, WW0, PART, W2P);
  k_reduce<<<BB, 128, 0, stream>>>(PART, W2P, E, A, INP2T);
  k_fc<<<OUTN/4, 256, 0, stream>>>(INP2T, fcW, fcb, out);
}

// Round 4
// 306.013 us; speedup vs baseline: 1.2964x; 1.2964x over previous
//
#include <hip/hip_runtime.h>

#define BB 64
#define NN 8192
#define MM 128
#define HH 512
#define KLSTM 896   // 384 (x|pr0|pr1) + 512 (h0)
#define JTOT 2048
#define COLS 658    // 134 (ro0) + 390 (wo0) + 134 (ro1)
#define OUTN 128
#define CHUNKS 32   // 8192/32 = 256 rows per chunk
#define PROW 388    // PART row stride: 3*128 + 1 (w2) padded to 16B multiple

__device__ __forceinline__ float sigf(float x){ return 1.0f/(1.0f+__expf(-x)); }
__device__ __forceinline__ float tanhf_f(float x){ return 1.0f - 2.0f/(__expf(2.0f*x)+1.0f); }
__device__ __forceinline__ float softplusf_(float x){ return (x>20.0f)? x : log1pf(expf(x)); }

// ---------- 1. LSTM gemm (inp built on the fly): gates[b][j] ----------
__global__ __launch_bounds__(1024) void k_lstm_gemm(
    const float* __restrict__ x, const float* __restrict__ pr,
    const float* __restrict__ h0,
    const float* __restrict__ Wih, const float* __restrict__ Whh,
    const float* __restrict__ bih, const float* __restrict__ bhh,
    float* __restrict__ gates)
{
  __shared__ float inp_s[64*65];   // [k][b]
  __shared__ float w_s[64*68];     // [k][j]
  int tid = threadIdx.x;
  int b = tid & 63, jl = tid >> 6;      // jl 0..15, owns 4 consecutive j
  int jbase = blockIdx.x*64;
  float ax=0.f, ay=0.f, az=0.f, aw=0.f;
  for (int kc=0; kc<KLSTM; kc+=64){
    #pragma unroll
    for (int i=0;i<4;i++){
      int idx = tid + i*1024;
      int kk = idx & 63, p = idx >> 6;
      int kglob = kc + kk;
      float iv;
      if (kglob < 128)      iv = x[p*128 + kglob];
      else if (kglob < 256) iv = pr[p*MM + (kglob-128)];
      else if (kglob < 384) iv = pr[BB*MM + p*MM + (kglob-256)];
      else                  iv = h0[p*HH + (kglob-384)];
      inp_s[kk*65+p] = iv;
      float wv = (kglob < 384) ? Wih[(size_t)(jbase+p)*384 + kglob]
                               : Whh[(size_t)(jbase+p)*512 + (kglob-384)];
      w_s[kk*68 + p] = wv;
    }
    __syncthreads();
    #pragma unroll 8
    for (int kk=0; kk<64; ++kk){
      float a = inp_s[kk*65 + b];
      const float4 w4 = *(const float4*)&w_s[kk*68 + jl*4];
      ax += a*w4.x; ay += a*w4.y; az += a*w4.z; aw += a*w4.w;
    }
    __syncthreads();
  }
  int j0 = jbase + jl*4;
  float4 o;
  o.x = ax + bih[j0+0] + bhh[j0+0];
  o.y = ay + bih[j0+1] + bhh[j0+1];
  o.z = az + bih[j0+2] + bhh[j0+2];
  o.w = aw + bih[j0+3] + bhh[j0+3];
  *(float4*)&gates[(size_t)b*JTOT + j0] = o;
}

// ---------- 2. head gemm (LSTM activation fused into staging) ----------
__global__ __launch_bounds__(1024) void k_head_gemm(
    const float* __restrict__ gates, const float* __restrict__ c0,
    const float* __restrict__ Wr, const float* __restrict__ br,
    const float* __restrict__ Ww, const float* __restrict__ bw,
    float* __restrict__ roall)
{
  __shared__ float c_s[64*65];   // [k][b]
  __shared__ float w_s[64*68];   // [k][col]
  int tid = threadIdx.x;
  int b = tid & 63, cl = tid >> 6;
  int cbase = blockIdx.x*64;
  float ac[4] = {0.f,0.f,0.f,0.f};
  for (int kc=0; kc<HH; kc+=64){
    #pragma unroll
    for (int i=0;i<4;i++){
      int idx = tid + i*1024;
      int kk = idx & 63, p = idx >> 6;
      int h = kc + kk;
      const float* g = gates + (size_t)p*JTOT;
      float i_ = sigf(g[h]);
      float f_ = sigf(g[HH + h]);
      float gg = tanhf_f(g[2*HH + h]);
      float o_ = sigf(g[3*HH + h]);
      float cn = f_*c0[p*HH + h] + i_*gg;
      c_s[kk*65+p] = o_*tanhf_f(cn);
      int col = cbase + p;
      float wv = 0.0f;
      if (col < 134)       wv = Wr[(size_t)col*HH + h];
      else if (col < 524)  wv = Ww[(size_t)(col-134)*HH + h];
      else if (col < COLS) wv = Wr[(size_t)(134 + col-524)*HH + h];
      w_s[kk*68 + p] = wv;
    }
    __syncthreads();
    #pragma unroll 8
    for (int kk=0; kk<64; ++kk){
      float a = c_s[kk*65 + b];
      const float4 w4 = *(const float4*)&w_s[kk*68 + cl*4];
      ac[0] += a*w4.x; ac[1] += a*w4.y; ac[2] += a*w4.z; ac[3] += a*w4.w;
    }
    __syncthreads();
  }
  #pragma unroll
  for (int t=0;t<4;t++){
    int col = cbase + cl*4 + t;
    if (col < COLS){
      float bias = (col<134)? br[col] : (col<524)? bw[col-134] : br[134 + col-524];
      roall[(size_t)b*COLS + col] = ac[t] + bias;
    }
  }
}

// ---------- 3. params: COEF8[b][m][8]={kr0,kw0,kr1,e*kr1,e,e2,a,a*e}, scal ----------
// scal rows 0..2 (r0,w0,r1): {beta,g,s0,s1,s2,gamma,knorm,-}; row 3: {a.kr1, a.a}
__global__ __launch_bounds__(128) void k_params(
    const float* __restrict__ roall, float* __restrict__ COEF8,
    float* __restrict__ scal)
{
  int b = blockIdx.x;
  int m = threadIdx.x;   // 128
  const float* ro = roall + (size_t)b*COLS;
  float k0 = ro[m], kw = ro[134+m], k1 = ro[524+m];
  float e  = sigf(ro[268+m]);
  float a  = ro[396+m];
  float* c8 = COEF8 + ((size_t)b*MM + m)*8;
  float4 cA = {k0, kw, k1, e*k1};
  float4 cB = {e, e*e, a, a*e};
  *(float4*)c8 = cA;
  *(float4*)(c8+4) = cB;
  // 5 reductions over m: k0^2, kw^2, k1^2, a*k1, a^2
  float r0=k0*k0, r1=kw*kw, r2=k1*k1, r3=a*k1, r4=a*a;
  #pragma unroll
  for (int off=32; off; off>>=1){
    r0 += __shfl_xor(r0, off);
    r1 += __shfl_xor(r1, off);
    r2 += __shfl_xor(r2, off);
    r3 += __shfl_xor(r3, off);
    r4 += __shfl_xor(r4, off);
  }
  __shared__ float wred[2][5];
  int lane = m & 63, w = m >> 6;
  if (lane == 0){
    wred[w][0]=r0; wred[w][1]=r1; wred[w][2]=r2; wred[w][3]=r3; wred[w][4]=r4;
  }
  __syncthreads();
  if (m < 3){
    float knsq = wred[0][m] + wred[1][m];
    float kn = fmaxf(sqrtf(knsq), 1e-8f);
    int base = (m==0)? 0 : (m==1)? 134 : 524;
    float beta  = softplusf_(ro[base+128]);
    float g     = sigf(ro[base+129]);
    float s0r = ro[base+130], s1r = ro[base+131], s2r = ro[base+132];
    float mx = fmaxf(s0r, fmaxf(s1r, s2r));
    float es0 = __expf(s0r-mx), es1 = __expf(s1r-mx), es2 = __expf(s2r-mx);
    float es = es0+es1+es2;
    float gamma = 1.0f + softplusf_(ro[base+133]);
    float* sc = scal + ((size_t)m*BB + b)*8;
    sc[0]=beta; sc[1]=g; sc[2]=es0/es; sc[3]=es1/es; sc[4]=es2/es; sc[5]=gamma; sc[6]=kn;
  }
  if (m == 3) scal[((size_t)3*BB + b)*8 + 0] = wred[0][3] + wred[1][3];  // a.kr1
  if (m == 4) scal[((size_t)3*BB + b)*8 + 1] = wred[0][4] + wred[1][4];  // a.a
}

// ---------- 4. pass A: lane-per-row via LDS transpose; 9 scalars, no shuffles ----------
// OUT9 layout [q][b][n], q: 0=v.kr0 1=v.kw0 2=|v|^2 3=v.kr1 4=v.(e*kr1)
//                         5=sum v^2 e  6=sum v^2 e^2  7=v.a  8=v.(a*e)
__global__ __launch_bounds__(256) void k_passA(
    const float* __restrict__ mem, const float* __restrict__ COEF8,
    float* __restrict__ OUT9)
{
  const size_t S = (size_t)BB*NN;
  int b = blockIdx.y, chunk = blockIdx.x;
  int tid = threadIdx.x;
  __shared__ float vtile[32][257];     // [kk][row], stride 257 -> conflict-free
  __shared__ float4 ctile[256];        // [m][2] float4 pairs
  ctile[tid] = ((const float4*)(COEF8 + (size_t)b*MM*8))[tid];
  int rowbase = chunk*256;
  float acc[9];
  #pragma unroll
  for (int q=0;q<9;q++) acc[q] = 0.f;
  for (int kc=0; kc<4; ++kc){
    __syncthreads();
    #pragma unroll
    for (int i=0;i<8;i++){
      int f = tid + i*256;          // [0,2048)
      int r = f >> 3, k4 = f & 7;
      float4 v = *(const float4*)(mem + ((size_t)b*NN + rowbase + r)*MM + kc*32 + k4*4);
      vtile[k4*4+0][r] = v.x;
      vtile[k4*4+1][r] = v.y;
      vtile[k4*4+2][r] = v.z;
      vtile[k4*4+3][r] = v.w;
    }
    __syncthreads();
    #pragma unroll
    for (int kk=0; kk<32; ++kk){
      int kg = kc*32 + kk;
      float4 cA = ctile[kg*2];      // kr0,kw0,kr1,ekr1 (uniform -> broadcast)
      float4 cB = ctile[kg*2+1];    // e,e2,a,ae
      float v  = vtile[kk][tid];
      float vv = v*v;
      acc[0] += v*cA.x;  acc[1] += v*cA.y;  acc[2] += vv;
      acc[3] += v*cA.z;  acc[4] += v*cA.w;
      acc[5] += vv*cB.x; acc[6] += vv*cB.y;
      acc[7] += v*cB.z;  acc[8] += v*cB.w;
    }
  }
  size_t p = (size_t)b*NN + rowbase + tid;
  #pragma unroll
  for (int q=0;q<9;q++) OUT9[(size_t)q*S + p] = acc[q];
}

// ---------- 5. addressing head 0 (read & write roles) ----------
__global__ __launch_bounds__(256) void k_addr0(
    const float* __restrict__ OUT9, const float* __restrict__ scal,
    const float* __restrict__ pwr, const float* __restrict__ pww,
    float* __restrict__ wout)
{
  const size_t S = (size_t)BB*NN;
  int b = blockIdx.x, which = blockIdx.y;
  const float* numb = OUT9 + (size_t)which*S + (size_t)b*NN;
  const float* ssb  = OUT9 + 2*S + (size_t)b*NN;
  const float* wprev = ((which==0)? pwr : pww) + (size_t)b*NN;
  float* wo = wout + (size_t)which*S + (size_t)b*NN;
  const float* sc = scal + ((size_t)which*BB + b)*8;
  float beta=sc[0], g=sc[1], s0=sc[2], s1=sc[3], s2=sc[4], gamma=sc[5], kn=sc[6];

  __shared__ float buf[NN];
  __shared__ float red[256];
  int tid = threadIdx.x;

  float lmax = -1e30f;
  for (int n=tid; n<NN; n+=256){
    float den = fmaxf(sqrtf(ssb[n]), 1e-8f) * kn;
    float l = beta * numb[n] / den;
    buf[n] = l;
    lmax = fmaxf(lmax, l);
  }
  red[tid] = lmax; __syncthreads();
  for (int s=128; s>0; s>>=1){ if (tid<s) red[tid]=fmaxf(red[tid],red[tid+s]); __syncthreads(); }
  lmax = red[0]; __syncthreads();
  float lsum = 0.f;
  for (int n=tid; n<NN; n+=256){ float e = __expf(buf[n]-lmax); buf[n]=e; lsum+=e; }
  red[tid] = lsum; __syncthreads();
  for (int s=128; s>0; s>>=1){ if (tid<s) red[tid]+=red[tid+s]; __syncthreads(); }
  float inv = 1.0f/red[0]; __syncthreads();
  for (int n=tid; n<NN; n+=256){ float wc = buf[n]*inv; buf[n] = g*wc + (1.0f-g)*wprev[n]; }
  __syncthreads();
  float wt_loc[32];
  float psum = 0.f;
  #pragma unroll
  for (int i=0;i<32;i++){
    int n = tid + i*256;
    float wm = buf[(n-1)&(NN-1)];
    float w0 = buf[n];
    float wp = buf[(n+1)&(NN-1)];
    float wt = s0*wm + s1*w0 + s2*wp;
    float p = __expf(gamma*__logf(wt));
    wt_loc[i] = p; psum += p;
  }
  red[tid] = psum; __syncthreads();
  for (int s=128; s>0; s>>=1){ if (tid<s) red[tid]+=red[tid+s]; __syncthreads(); }
  float invp = 1.0f/(red[0] + 1e-16f);
  #pragma unroll
  for (int i=0;i<32;i++) wo[tid + i*256] = wt_loc[i]*invp;
}

// ---------- 6. addressing head 1 read (num/norm reconstructed, no mem read) ----------
__global__ __launch_bounds__(256) void k_addr1(
    const float* __restrict__ OUT9, const float* __restrict__ ww0,
    const float* __restrict__ scal, const float* __restrict__ wprev,
    float* __restrict__ wout)
{
  const size_t S = (size_t)BB*NN;
  int b = blockIdx.x;
  const float* pb  = OUT9 + (size_t)b*NN;
  const float* wwb = ww0 + (size_t)b*NN;
  const float* wp  = wprev + (size_t)b*NN;
  float* wo = wout + (size_t)b*NN;
  const float* sc = scal + ((size_t)2*BB + b)*8;
  float beta=sc[0], g=sc[1], s0=sc[2], s1=sc[3], s2=sc[4], gamma=sc[5], kn=sc[6];
  const float* sc3 = scal + ((size_t)3*BB + b)*8;
  float akr1 = sc3[0], aa = sc3[1];

  __shared__ float buf[NN];
  __shared__ float red[256];
  int tid = threadIdx.x;

  float lmax = -1e30f;
  for (int n=tid; n<NN; n+=256){
    float ss = pb[2*S+n], t3 = pb[3*S+n], t4 = pb[4*S+n];
    float t5 = pb[5*S+n], t6 = pb[6*S+n], t7 = pb[7*S+n], t8 = pb[8*S+n];
    float w = wwb[n];
    float num  = t3 + w*(akr1 - t4);
    float n1sq = ss + 2.0f*w*(t7 - t5) + w*w*(t6 + aa - 2.0f*t8);
    float nrm = sqrtf(fmaxf(n1sq, 0.f));
    float l = beta * num / (fmaxf(nrm, 1e-8f) * kn);
    buf[n] = l;
    lmax = fmaxf(lmax, l);
  }
  red[tid] = lmax; __syncthreads();
  for (int s=128; s>0; s>>=1){ if (tid<s) red[tid]=fmaxf(red[tid],red[tid+s]); __syncthreads(); }
  lmax = red[0]; __syncthreads();
  float lsum = 0.f;
  for (int n=tid; n<NN; n+=256){ float e = __expf(buf[n]-lmax); buf[n]=e; lsum+=e; }
  red[tid] = lsum; __syncthreads();
  for (int s=128; s>0; s>>=1){ if (tid<s) red[tid]+=red[tid+s]; __syncthreads(); }
  float inv = 1.0f/red[0]; __syncthreads();
  for (int n=tid; n<NN; n+=256){ float wc = buf[n]*inv; buf[n] = g*wc + (1.0f-g)*wp[n]; }
  __syncthreads();
  float wt_loc[32];
  float psum = 0.f;
  #pragma unroll
  for (int i=0;i<32;i++){
    int n = tid + i*256;
    float wm = buf[(n-1)&(NN-1)];
    float w0 = buf[n];
    float wpv = buf[(n+1)&(NN-1)];
    float wt = s0*wm + s1*w0 + s2*wpv;
    float p = __expf(gamma*__logf(wt));
    wt_loc[i] = p; psum += p;
  }
  red[tid] = psum; __syncthreads();
  for (int s=128; s>0; s>>=1){ if (tid<s) red[tid]+=red[tid+s]; __syncthreads(); }
  float invp = 1.0f/(red[0] + 1e-16f);
  #pragma unroll
  for (int i=0;i<32;i++) wo[tid + i*256] = wt_loc[i]*invp;
}

// ---------- 7. pass F: second read of mem0, 3 weighted row-sums + w2 ----------
// PART layout [b][chunk][PROW]: 3*128 sums + w2 at 384
__global__ __launch_bounds__(256) void k_passF(
    const float* __restrict__ mem, const float* __restrict__ wr0,
    const float* __restrict__ wr1, const float* __restrict__ ww0,
    float* __restrict__ part)
{
  int b = blockIdx.y, chunk = blockIdx.x;
  int tid = threadIdx.x, ty = tid>>5, lane = tid&31;
  float4 a0 = {0.f,0.f,0.f,0.f}, a1 = a0, a2 = a0;
  float w2 = 0.f;
  for (int it=0; it<32; ++it){
    int n = chunk*256 + it*8 + ty;
    size_t p = (size_t)b*NN + n;
    const float4* row = (const float4*)(mem + p*MM);
    float4 v = row[lane];
    float w0r = wr0[p], w1r = wr1[p], wwr = ww0[p];
    float w12 = w1r*wwr;
    a0.x += w0r*v.x; a0.y += w0r*v.y; a0.z += w0r*v.z; a0.w += w0r*v.w;
    a1.x += w1r*v.x; a1.y += w1r*v.y; a1.z += w1r*v.z; a1.w += w1r*v.w;
    a2.x += w12*v.x; a2.y += w12*v.y; a2.z += w12*v.z; a2.w += w12*v.w;
    if (lane==0) w2 += w12;
  }
  __shared__ float4 sred[256];
  __shared__ float w2s[8];
  float* prow = part + (size_t)(b*CHUNKS + chunk)*PROW;
  float4 accs[3] = {a0,a1,a2};
  #pragma unroll
  for (int q=0;q<3;q++){
    sred[tid] = accs[q];
    __syncthreads();
    if (ty == 0){
      float4 s = {0.f,0.f,0.f,0.f};
      #pragma unroll
      for (int r=0;r<8;r++){
        float4 t = sred[r*32 + lane];
        s.x += t.x; s.y += t.y; s.z += t.z; s.w += t.w;
      }
      ((float4*)(prow + q*MM))[lane] = s;
    }
    __syncthreads();
  }
  if (lane==0) w2s[ty] = w2;
  __syncthreads();
  if (tid==0){
    float s = 0.f;
    #pragma unroll
    for (int r=0;r<8;r++) s += w2s[r];
    prow[384] = s;
  }
}

// ---------- 8. tail: reduce partials + fc + sigmoid ----------
__global__ __launch_bounds__(256) void k_tail(
    const float* __restrict__ part, const float* __restrict__ COEF8,
    const float* __restrict__ fcW, const float* __restrict__ fcb,
    float* __restrict__ out)
{
  int b = blockIdx.x;
  int tid = threadIdx.x;
  __shared__ float s_lds[384];
  __shared__ float inp2[256];
  __shared__ float w2sh;
  const float* pbase = part + (size_t)b*CHUNKS*PROW;
  for (int idx=tid; idx<384; idx+=256){
    float s = 0.f;
    for (int c=0;c<CHUNKS;c++) s += pbase[(size_t)c*PROW + idx];
    s_lds[idx] = s;
  }
  if (tid == 0){
    float w = 0.f;
    for (int c=0;c<CHUNKS;c++) w += pbase[(size_t)c*PROW + 384];
    w2sh = w;
  }
  __syncthreads();
  if (tid < 128){
    int m = tid;
    float e = COEF8[((size_t)b*MM + m)*8 + 4];
    float a = COEF8[((size_t)b*MM + m)*8 + 6];
    inp2[m] = s_lds[m];
    inp2[MM + m] = s_lds[MM + m] - e*s_lds[2*MM + m] + w2sh*a;
  }
  __syncthreads();
  if (tid < 128){
    int o = tid;
    float acc = fcb[o];
    const float4* wrow = (const float4*)(fcW + (size_t)o*(2*MM));
    const float4* i2 = (const float4*)inp2;
    #pragma unroll 8
    for (int k4=0; k4<64; ++k4){
      float4 w = wrow[k4];
      float4 v = i2[k4];
      acc += w.x*v.x + w.y*v.y + w.z*v.z + w.w*v.w;
    }
    out[(size_t)b*OUTN + o] = sigf(acc);
  }
}

extern "C" void kernel_launch(void* const* d_in, const int* in_sizes, int n_in,
                              void* d_out, int out_size, void* d_ws, size_t ws_size,
                              hipStream_t stream) {
  const float* x   = (const float*)d_in[0];
  const float* pr  = (const float*)d_in[1];
  const float* h0  = (const float*)d_in[2];
  const float* c0  = (const float*)d_in[3];
  const float* pwr = (const float*)d_in[4];
  const float* pww = (const float*)d_in[5];
  const float* mem = (const float*)d_in[6];
  const float* Wih = (const float*)d_in[7];
  const float* Whh = (const float*)d_in[8];
  const float* bih = (const float*)d_in[9];
  const float* bhh = (const float*)d_in[10];
  const float* Wr  = (const float*)d_in[11];
  const float* br  = (const float*)d_in[12];
  const float* Ww  = (const float*)d_in[13];
  const float* bw  = (const float*)d_in[14];
  const float* fcW = (const float*)d_in[15];
  const float* fcb = (const float*)d_in[16];
  float* out = (float*)d_out;

  float* ws = (float*)d_ws;
  size_t off = 0;
  auto alloc = [&](size_t n){ float* p = ws + off; off += n; return p; };
  const size_t S = (size_t)BB*NN;
  float* GATES = alloc((size_t)BB*JTOT);
  float* ROALL = alloc((size_t)BB*COLS + 14);        // pad to 16B boundary
  float* COEF8 = alloc((size_t)BB*MM*8);
  float* SCAL  = alloc((size_t)4*BB*8);
  float* OUT9  = alloc(9*S);
  float* WR0   = alloc(S);
  float* WW0   = alloc(S);     // must stay adjacent to WR0
  float* WR1   = alloc(S);
  float* PART  = alloc((size_t)BB*CHUNKS*PROW);
  (void)ws_size; (void)in_sizes; (void)n_in; (void)out_size; (void)WW0;

  k_lstm_gemm<<<JTOT/64, 1024, 0, stream>>>(x, pr, h0, Wih, Whh, bih, bhh, GATES);
  k_head_gemm<<<(COLS+63)/64, 1024, 0, stream>>>(GATES, c0, Wr, br, Ww, bw, ROALL);
  k_params<<<BB, 128, 0, stream>>>(ROALL, COEF8, SCAL);
  k_passA<<<dim3(CHUNKS,BB), 256, 0, stream>>>(mem, COEF8, OUT9);
  k_addr0<<<dim3(BB,2), 256, 0, stream>>>(OUT9, SCAL, pwr, pww, WR0);
  k_addr1<<<BB, 256, 0, stream>>>(OUT9, WW0, SCAL, pwr + S, WR1);
  k_passF<<<dim3(CHUNKS,BB), 256, 0, stream>>>(mem, WR0, WR1, WW0, PART);
  k_tail<<<BB, 256, 0, stream>>>(PART, COEF8, fcW, fcb, out);
}